// Round 4
// baseline (561.350 us; speedup 1.0000x reference)
//
#include <hip/hip_runtime.h>
#include <math.h>

typedef short short8 __attribute__((ext_vector_type(8)));
typedef short short4v __attribute__((ext_vector_type(4)));
typedef float float4v __attribute__((ext_vector_type(4)));
#define AS1 __attribute__((address_space(1)))
#define AS3 __attribute__((address_space(3)))

__device__ __forceinline__ float b2f(ushort u) {
    unsigned v = ((unsigned)u) << 16; float f; __builtin_memcpy(&f, &v, 4); return f;
}
__device__ __forceinline__ ushort f2b(float f) {
    unsigned v; __builtin_memcpy(&v, &f, 4);
    unsigned r = (v + 0x7fffu + ((v >> 16) & 1u)) >> 16;
    return (ushort)r;
}

// 16x16x16 bf16 MFMA (K=16): prefer native builtin, else emulate via zero-padded K=32.
__device__ __forceinline__ float4v pv_mfma(short4v a, short4v b, float4v c) {
#if __has_builtin(__builtin_amdgcn_mfma_f32_16x16x16_bf16)
    return __builtin_amdgcn_mfma_f32_16x16x16_bf16(a, b, c, 0, 0, 0);
#elif __has_builtin(__builtin_amdgcn_mfma_f32_16x16x16bf16_1k)
    return __builtin_amdgcn_mfma_f32_16x16x16bf16_1k(a, b, c, 0, 0, 0);
#else
    short8 a8 = {a[0], a[1], a[2], a[3], 0, 0, 0, 0};
    short8 b8 = {b[0], b[1], b[2], b[3], 0, 0, 0, 0};
    return __builtin_amdgcn_mfma_f32_16x16x32_bf16(a8, b8, c, 0, 0, 0);
#endif
}

// ---------- fp32 -> bf16 convert (optional zero-pad rows) ----------
__global__ void cvt_pad(const float* __restrict__ src, ushort* __restrict__ dst,
                        int src_rows, int cols, int total4) {
    int i = blockIdx.x * 256 + threadIdx.x;
    if (i >= total4) return;
    size_t e = (size_t)i * 4;
    int r = (int)(e / (size_t)cols);
    ushort4 o;
    if (r < src_rows) {
        float4 v = *(const float4*)(src + e);
        o.x = f2b(v.x); o.y = f2b(v.y); o.z = f2b(v.z); o.w = f2b(v.w);
    } else {
        o.x = 0; o.y = 0; o.z = 0; o.w = 0;
    }
    *(ushort4*)(dst + e) = o;
}

// ---------- bf16 GEMM: C(MxN) = A(MxK) @ B(NxK)^T, strided ----------
__global__ __launch_bounds__(256)
void gemm_bt(const ushort* __restrict__ A, const ushort* __restrict__ B,
             void* __restrict__ Cv, int K, int lda, int ldb, int ldc, int f32out) {
    __shared__ ushort sA[128 * 32];
    __shared__ ushort sB[128 * 32];
    const int tid = threadIdx.x;
    const int wave = tid >> 6, lane = tid & 63;
    const int bm = blockIdx.y * 128, bn = blockIdx.x * 128;
    const int wm = (wave >> 1) * 64, wn = (wave & 1) * 64;
    float4v acc[4][4] = {};

    const int srow = wave * 32 + (lane >> 2);
    const int skc = (lane & 3) * 8;
    const ushort* Ag = A + (size_t)(bm + srow) * lda + skc;
    const ushort* Bg = B + (size_t)(bn + srow) * ldb + skc;
    ushort* sAw = sA + (wave * 32) * 32;
    ushort* sBw = sB + (wave * 32) * 32;

    for (int k0 = 0; k0 < K; k0 += 32) {
        __builtin_amdgcn_global_load_lds((const AS1 void*)(Ag + k0), (AS3 void*)sAw, 16, 0, 0);
        __builtin_amdgcn_global_load_lds((const AS1 void*)(Ag + (size_t)16 * lda + k0),
                                         (AS3 void*)(sAw + 16 * 32), 16, 0, 0);
        __builtin_amdgcn_global_load_lds((const AS1 void*)(Bg + k0), (AS3 void*)sBw, 16, 0, 0);
        __builtin_amdgcn_global_load_lds((const AS1 void*)(Bg + (size_t)16 * ldb + k0),
                                         (AS3 void*)(sBw + 16 * 32), 16, 0, 0);
        __syncthreads();
        short8 af[4], bfr[4];
#pragma unroll
        for (int i = 0; i < 4; ++i) {
            af[i]  = *(const short8*)(sA + (wm + i * 16 + (lane & 15)) * 32 + (lane >> 4) * 8);
            bfr[i] = *(const short8*)(sB + (wn + i * 16 + (lane & 15)) * 32 + (lane >> 4) * 8);
        }
#pragma unroll
        for (int i = 0; i < 4; ++i)
#pragma unroll
            for (int j = 0; j < 4; ++j)
                acc[i][j] = __builtin_amdgcn_mfma_f32_16x16x32_bf16(af[i], bfr[j], acc[i][j], 0, 0, 0);
        __syncthreads();
    }
#pragma unroll
    for (int i = 0; i < 4; ++i) {
        int row0 = bm + wm + i * 16 + (lane >> 4) * 4;
#pragma unroll
        for (int j = 0; j < 4; ++j) {
            int col = bn + wn + j * 16 + (lane & 15);
            if (f32out) {
                float* C = (float*)Cv;
#pragma unroll
                for (int r = 0; r < 4; ++r)
                    C[(size_t)(row0 + r) * ldc + col] = acc[i][j][r];
            } else {
                ushort* C = (ushort*)Cv;
#pragma unroll
                for (int r = 0; r < 4; ++r)
                    C[(size_t)(row0 + r) * ldc + col] = f2b(acc[i][j][r]);
            }
        }
    }
}

// ---------- rmsnorm (in-place, one block per row, strided) ----------
__global__ void rmsnorm_inplace(ushort* __restrict__ d, const float* __restrict__ w,
                                int cols, int ld) {
    int row = blockIdx.x, tid = threadIdx.x;
    ushort* p = d + (size_t)row * ld;
    float ss = 0.f;
    for (int i = tid; i < cols; i += 256) { float v = b2f(p[i]); ss += v * v; }
#pragma unroll
    for (int off = 32; off >= 1; off >>= 1) ss += __shfl_xor(ss, off);
    __shared__ float red[4];
    if ((tid & 63) == 0) red[tid >> 6] = ss;
    __syncthreads();
    float tot = red[0] + red[1] + red[2] + red[3];
    float rs = rsqrtf(tot / (float)cols + 1e-6f);
    for (int i = tid; i < cols; i += 256) p[i] = f2b(b2f(p[i]) * rs * w[i]);
}

// ---------- kv norm (cols 0..512) + k_pe rope (cols 512..576), strided ----------
__global__ void kvnorm_rope(const ushort* __restrict__ kvraw, const float* __restrict__ w,
                            const float* __restrict__ freqs, ushort* __restrict__ kvc,
                            ushort* __restrict__ kpe, int ld) {
    int row = blockIdx.x, tid = threadIdx.x;
    int s = row & 2047;
    const ushort* p = kvraw + (size_t)row * ld;
    float v0 = b2f(p[tid]), v1 = b2f(p[tid + 256]);
    float ss = v0 * v0 + v1 * v1;
#pragma unroll
    for (int off = 32; off >= 1; off >>= 1) ss += __shfl_xor(ss, off);
    __shared__ float red[4];
    if ((tid & 63) == 0) red[tid >> 6] = ss;
    __syncthreads();
    float tot = red[0] + red[1] + red[2] + red[3];
    float rs = rsqrtf(tot / 512.f + 1e-6f);
    kvc[(size_t)row * 512 + tid] = f2b(v0 * rs * w[tid]);
    kvc[(size_t)row * 512 + tid + 256] = f2b(v1 * rs * w[tid + 256]);
    if (tid < 32) {
        float re = b2f(p[512 + 2 * tid]), im = b2f(p[512 + 2 * tid + 1]);
        float cs = freqs[(s * 32 + tid) * 2], sn = freqs[(s * 32 + tid) * 2 + 1];
        kpe[(size_t)row * 64 + 2 * tid] = f2b(re * cs - im * sn);
        kpe[(size_t)row * 64 + 2 * tid + 1] = f2b(re * sn + im * cs);
    }
}

// ---------- rope on q_pe (last 64 of each 192-dim head) ----------
__global__ void qrope(ushort* __restrict__ q, const float* __restrict__ freqs) {
    int idx = blockIdx.x * 256 + threadIdx.x;
    int i = idx & 31;
    int h = (idx >> 5) & 15;
    int srow = idx >> 9;
    int s = srow & 2047;
    ushort* p = q + ((size_t)srow * 16 + h) * 192 + 128 + 2 * i;
    float re = b2f(p[0]), im = b2f(p[1]);
    float cs = freqs[(s * 32 + i) * 2], sn = freqs[(s * 32 + i) * 2 + 1];
    p[0] = f2b(re * cs - im * sn);
    p[1] = f2b(re * sn + im * cs);
}

// ---------- K repack: Kfull[b][h][s][200] = k_nope(128) | k_pe(64) | pad(8) ----------
__global__ void k_repack(const ushort* __restrict__ kvb, const ushort* __restrict__ kpe,
                         ushort* __restrict__ Kfull) {
    int tid = threadIdx.x;
    int row = blockIdx.x * 8 + (tid >> 5);   // row = bh*2048 + s
    int c = tid & 31;
    int bh = row >> 11, s = row & 2047;
    int b = bh >> 4, h = bh & 15;
    size_t sg = (size_t)b * 2048 + s;
    short8 v = {0, 0, 0, 0, 0, 0, 0, 0};
    if (c < 16)      v = *(const short8*)(kvb + sg * 4096 + h * 256 + c * 8);
    else if (c < 24) v = *(const short8*)(kpe + sg * 64 + (c - 16) * 8);
    if (c < 25) *(short8*)(Kfull + (size_t)row * 200 + c * 8) = v;
}

// ---------- V repack/transpose: Vt[bh][kt][128][72] (cols 64..71 pad) ----------
__global__ __launch_bounds__(256)
void v_repack(const ushort* __restrict__ kvb, ushort* __restrict__ Vt) {
    __shared__ ushort sT[64][136];
    int tid = threadIdx.x;
    int kt = blockIdx.x, bh = blockIdx.y;
    int b = bh >> 4, h = bh & 15;
#pragma unroll
    for (int k = 0; k < 4; ++k) {
        int id = k * 256 + tid;
        int r = id >> 4, c8 = id & 15;
        size_t sg = (size_t)b * 2048 + kt * 64 + r;
        *(short8*)(&sT[r][c8 * 8]) = *(const short8*)(kvb + sg * 4096 + h * 256 + 128 + c8 * 8);
    }
    __syncthreads();
    int d = tid >> 1, half = tid & 1;
    ushort tmp[32];
#pragma unroll
    for (int i = 0; i < 32; ++i) tmp[i] = sT[half * 32 + i][d];
    ushort* dst = Vt + (((size_t)bh * 32 + kt) * 128 + d) * 72 + half * 32;
#pragma unroll
    for (int i = 0; i < 4; ++i) *(short8*)(dst + i * 8) = *(const short8*)(tmp + i * 8);
}

// ---------- causal flash attention, S^T formulation ----------
// grid (32 q-tiles longest-first, 32 bh), 256 threads. Wave w owns q rows [qt*64+w*16,+16).
// S^T = K·Q^T : C layout puts q in lane&15, kv in quad*4+r -> softmax needs only
// shfl_xor(16,32); S^T accumulator regs ARE the P^T B-fragment for O^T = Vt·P^T (K=16).
__global__ __launch_bounds__(256)
void mla_attn3(const ushort* __restrict__ q, const ushort* __restrict__ Kfull,
               const ushort* __restrict__ Vt, ushort* __restrict__ out, float scale) {
    __shared__ ushort sK[64 * 200];
    __shared__ ushort sV[128 * 72];
    const int tid = threadIdx.x, wave = tid >> 6, lane = tid & 63;
    const int lq = lane & 15, quad = lane >> 4;
    const int qt = 31 - blockIdx.x;           // longest-first
    const int bh = blockIdx.y;
    const int b = bh >> 4, h = bh & 15;
    const ushort* Kb = Kfull + (size_t)bh * 2048 * 200;
    const ushort* Vb = Vt + (size_t)bh * 32 * 128 * 72;

    const int q_abs = qt * 64 + wave * 16 + lq;   // this lane's q column
    const ushort* qp = q + ((size_t)(b * 2048 + q_abs) * 16 + h) * 192 + quad * 8;
    short8 qf[6];
#pragma unroll
    for (int c = 0; c < 6; ++c) qf[c] = *(const short8*)(qp + c * 32);

    float4v oacc[8] = {};                         // O^T: d = dt*16+quad*4+r, q = lq
    float m_i = -INFINITY, l_i = 0.f;

    for (int kt = 0; kt <= qt; ++kt) {
        const ushort* Ksrc = Kb + (size_t)kt * 64 * 200;
        const ushort* Vsrc = Vb + (size_t)kt * 128 * 72;
#pragma unroll
        for (int i = 0; i < 7; ++i) {
            int s0 = i * 256 + wave * 64;
            if (s0 < 1600)
                __builtin_amdgcn_global_load_lds((const AS1 void*)(Ksrc + (size_t)(s0 + lane) * 8),
                                                 (AS3 void*)(sK + s0 * 8), 16, 0, 0);
        }
#pragma unroll
        for (int i = 0; i < 5; ++i) {
            int s0 = i * 256 + wave * 64;
            if (s0 < 1152)
                __builtin_amdgcn_global_load_lds((const AS1 void*)(Vsrc + (size_t)(s0 + lane) * 8),
                                                 (AS3 void*)(sV + s0 * 8), 16, 0, 0);
        }
        __syncthreads();
        // S^T = K·Q^T : A = K row frag (m=kv), B = Q row frag (n=q)
        float4v sc[4];
#pragma unroll
        for (int ct = 0; ct < 4; ++ct) {
            float4v a = {0.f, 0.f, 0.f, 0.f};
#pragma unroll
            for (int c = 0; c < 6; ++c) {
                short8 kf = *(const short8*)(sK + (ct * 16 + lq) * 200 + c * 32 + quad * 8);
                a = __builtin_amdgcn_mfma_f32_16x16x32_bf16(kf, qf[c], a, 0, 0, 0);
            }
            sc[ct] = a;
        }
        // scale + causal mask + online softmax (per q column = per lane)
        float mx = m_i;
#pragma unroll
        for (int ct = 0; ct < 4; ++ct)
#pragma unroll
            for (int r = 0; r < 4; ++r) {
                float v = sc[ct][r] * scale;
                int kv = kt * 64 + ct * 16 + quad * 4 + r;
                if (kv > q_abs) v = -INFINITY;    // only triggers when kt==qt
                sc[ct][r] = v;
                mx = fmaxf(mx, v);
            }
        mx = fmaxf(mx, __shfl_xor(mx, 16));
        mx = fmaxf(mx, __shfl_xor(mx, 32));
        float alpha = __expf(m_i - mx);
        m_i = mx;
        float ps = 0.f;
        short4v pf[4];
#pragma unroll
        for (int ct = 0; ct < 4; ++ct)
#pragma unroll
            for (int r = 0; r < 4; ++r) {
                float pv = __expf(sc[ct][r] - mx);
                ps += pv;
                pf[ct][r] = (short)f2b(pv);
            }
        ps += __shfl_xor(ps, 16);
        ps += __shfl_xor(ps, 32);
        l_i = l_i * alpha + ps;
#pragma unroll
        for (int dt = 0; dt < 8; ++dt)
#pragma unroll
            for (int r = 0; r < 4; ++r) oacc[dt][r] *= alpha;
        // O^T += Vt·P^T  (A = Vt frag m=d,k=kv; B = pf n=q,k=kv)
#pragma unroll
        for (int dt = 0; dt < 8; ++dt)
#pragma unroll
            for (int ct = 0; ct < 4; ++ct) {
                short4v vf = *(const short4v*)(sV + (dt * 16 + lq) * 72 + ct * 16 + quad * 4);
                oacc[dt] = pv_mfma(vf, pf[ct], oacc[dt]);
            }
        __syncthreads();
    }
    float inv = 1.f / l_i;
#pragma unroll
    for (int dt = 0; dt < 8; ++dt) {
        ushort4 o;
        o.x = f2b(oacc[dt][0] * inv);
        o.y = f2b(oacc[dt][1] * inv);
        o.z = f2b(oacc[dt][2] * inv);
        o.w = f2b(oacc[dt][3] * inv);
        *(ushort4*)(out + ((size_t)(b * 2048 + q_abs) * 16 + h) * 128 + dt * 16 + quad * 4) = o;
    }
}

// ---------- launch ----------
extern "C" void kernel_launch(void* const* d_in, const int* in_sizes, int n_in,
                              void* d_out, int out_size, void* d_ws, size_t ws_size,
                              hipStream_t stream) {
    const float* x     = (const float*)d_in[0];
    const float* freqs = (const float*)d_in[2];
    const float* wq_a  = (const float*)d_in[3];
    const float* qnw   = (const float*)d_in[4];
    const float* wq_b  = (const float*)d_in[5];
    const float* wkv_a = (const float*)d_in[6];
    const float* kvnw  = (const float*)d_in[7];
    const float* wkv_b = (const float*)d_in[8];
    const float* wo    = (const float*)d_in[9];

    char* ws = (char*)d_ws;
    size_t off = 0;
    auto alloc = [&](size_t n) { char* p = ws + off; off += (n + 255) & ~(size_t)255; return p; };
    ushort* xb    = (ushort*)alloc(4096ull * 2048 * 2);   // dead after fused a-gemm
    ushort* wqkva = (ushort*)alloc(2176ull * 2048 * 2);   // wq_a rows 0..1535, wkv_a rows 1536..2111, pad..2175
    ushort* wqbb  = (ushort*)alloc(3072ull * 1536 * 2);   // dead after q_b gemm
    ushort* wkvbb = (ushort*)alloc(4096ull * 512 * 2);    // dead after kv_b gemm
    ushort* wob   = (ushort*)alloc(2048ull * 2048 * 2);   // live until final gemm
    ushort* qakv  = (ushort*)alloc(4096ull * 2176 * 2);   // qa cols 0..1535 | kvraw cols 1536..2111
    ushort* kvc   = (ushort*)alloc(4096ull * 512 * 2);
    ushort* kpe   = (ushort*)alloc(4096ull * 64 * 2);
    ushort* qfull = (ushort*)alloc(4096ull * 3072 * 2);
    ushort* kvbuf = (ushort*)alloc(4096ull * 4096 * 2);
    ushort* attno = (ushort*)alloc(4096ull * 2048 * 2);
    if (off > ws_size) return;
    // Aliased late buffers over dead regions:
    // Kfull 26.2 MB over xb+wqkva+wqbb (35.1 MB); Vt 18.9 MB over qakv+kvc (22.0 MB).
    ushort* Kfull = (ushort*)xb;
    ushort* Vt = (ushort*)qakv;

    auto cvt = [&](const float* s, ushort* dd, int sr, int cols, size_t dtot) {
        int t4 = (int)(dtot / 4);
        cvt_pad<<<(t4 + 255) / 256, 256, 0, stream>>>(s, dd, sr, cols, t4);
    };
    cvt(x, xb, 4096, 2048, 4096ull * 2048);
    cvt(wq_a, wqkva, 1536, 2048, 1536ull * 2048);
    cvt(wkv_a, wqkva + 1536ull * 2048, 576, 2048, 640ull * 2048);
    cvt(wq_b, wqbb, 3072, 1536, 3072ull * 1536);
    cvt(wkv_b, wkvbb, 4096, 512, 4096ull * 512);
    cvt(wo, wob, 2048, 2048, 2048ull * 2048);

    // fused q_a + kv_a projection: [4096 x 2048] @ [2176 x 2048]^T
    gemm_bt<<<dim3(17, 32), 256, 0, stream>>>(xb, wqkva, qakv, 2048, 2048, 2048, 2176, 0);
    rmsnorm_inplace<<<4096, 256, 0, stream>>>(qakv, qnw, 1536, 2176);
    kvnorm_rope<<<4096, 256, 0, stream>>>(qakv + 1536, kvnw, freqs, kvc, kpe, 2176);
    gemm_bt<<<dim3(24, 32), 256, 0, stream>>>(qakv, wqbb, qfull, 1536, 2176, 1536, 3072, 0);
    qrope<<<8192, 256, 0, stream>>>(qfull, freqs);
    gemm_bt<<<dim3(32, 32), 256, 0, stream>>>(kvc, wkvbb, kvbuf, 512, 512, 512, 4096, 0);
    // ---- repack (xb/wqkva/wqbb and qakv/kvc are dead from here) ----
    k_repack<<<8192, 256, 0, stream>>>(kvbuf, kpe, Kfull);
    v_repack<<<dim3(32, 32), 256, 0, stream>>>(kvbuf, Vt);
    const float scale = 1.0f / sqrtf(192.0f);
    mla_attn3<<<dim3(32, 32), 256, 0, stream>>>(qfull, Kfull, Vt, attno, scale);
    gemm_bt<<<dim3(16, 32), 256, 0, stream>>>(attno, wob, (float*)d_out, 2048, 2048, 2048, 2048, 1);
}